// Round 5
// baseline (122.360 us; speedup 1.0000x reference)
//
#include <hip/hip_runtime.h>

// CVXPolicy_Quadcopter R11: MFMA rewrite (R10 + compile fix: split2 returns
// packed pair by value; vector elements aren't lvalue-bindable to unsigned&).
// GEMM1: Y[B,100] = X[B,14] @ W1'[14,100]  (bias as const-1 input col, K pad 32)
// tanh (fp32, exp2 form), GEMM2: P[B,6] = th[B,100] @ W2c[100,6] (K pad 128)
// Both GEMMs via v_mfma_f32_16x16x32_bf16 with split-bf16 (hi+lo, 3 products:
// hh+hl+lh; dropped ll term ~2^-16 rel) => fp32-grade accuracy on MFMA pipe.
// Weights pre-packed into per-lane MFMA fragments by pack_weights; each wave
// keeps all B-fragments resident in VGPRs (~88) across its ~10 m-tiles.
// A/B fragment k-mapping only needs A-pack/B-pack CONSISTENCY (any k bijection
// cancels inside the MFMA dot product); C/D layout is the HW-verified
// col=lane&15, row=(lane>>4)*4+reg. Per-wave LDS tile ([16][132] f32,
// pad-stride 132 => conflict-free b128 reads) transposes Y for GEMM2-A and a
// [16][8] P tile for the per-row Lambert epilogue. No barriers (waves indep).

constexpr int S = 12;   // z features
constexpr int H = 100;  // hidden
#define TWO_LOG2E 2.8853900817779268f

typedef float f32x4 __attribute__((ext_vector_type(4)));
typedef __bf16 bf16x8 __attribute__((ext_vector_type(8)));
typedef unsigned int uint4v __attribute__((ext_vector_type(4)));

struct HiLo { unsigned h, l; };

__device__ __forceinline__ float fast_rcp(float x) {
    return __builtin_amdgcn_rcpf(x);
}

// split f32 pair into (hi-bf16 pair, lo-bf16 pair) packed words.
// elem (2d) -> low 16 bits, elem (2d+1) -> high 16 bits (matches pack_weights).
__device__ __forceinline__ HiLo split2(float f0, float f1) {
    unsigned b0 = __float_as_uint(f0), b1 = __float_as_uint(f1);
    float h0 = __uint_as_float(b0 & 0xffff0000u);
    float h1 = __uint_as_float(b1 & 0xffff0000u);
    unsigned l0 = __float_as_uint(f0 - h0) >> 16;
    unsigned l1 = __float_as_uint(f1 - h1) >> 16;
    HiLo r;
    r.h = (b0 >> 16) | (b1 & 0xffff0000u);
    r.l = l0 | (l1 << 16);
    return r;
}

// ws layout (dwords): ws1[ (t*2+p)*64 + lane ][d]  t<7 : 3584 dwords
//                     ws2 at 3584 + [ (s*2+p)*64 + lane ][d]  s<4 : 2048 dwords
__global__ __launch_bounds__(256) void pack_weights(
    const float* __restrict__ W1, const float* __restrict__ b1,
    const float* __restrict__ W2, float* __restrict__ ws)
{
    int idx = blockIdx.x * 256 + threadIdx.x;
    if (idx >= 5632) return;
    unsigned halves[2];
    if (idx < 3584) {
        int d = idx & 3, lane = (idx >> 2) & 63, tp = idx >> 8;
        int t = tp >> 1, p = tp & 1;
        int g = lane >> 4, n = (t << 4) + (lane & 15);
        #pragma unroll
        for (int h = 0; h < 2; ++h) {
            int k = g * 8 + 2 * d + h;
            float f = 0.0f;
            if (n < H) {
                if (k < 13)       f = W1[k * H + n];
                else if (k == 13) f = b1[n];
            }
            unsigned bb = __float_as_uint(f);
            unsigned hb = bb >> 16;
            float hf = __uint_as_float(bb & 0xffff0000u);
            unsigned lb = __float_as_uint(f - hf) >> 16;
            halves[h] = p ? lb : hb;
        }
    } else {
        int r = idx - 3584;
        int d = r & 3, lane = (r >> 2) & 63, sp = r >> 8;
        int s = sp >> 1, p = sp & 1;
        int g = lane >> 4, c = lane & 15;
        #pragma unroll
        for (int h = 0; h < 2; ++h) {
            int k = s * 32 + g * 8 + 2 * d + h;
            float f = (k < H && c < 6) ? W2[k * S + 6 + c] : 0.0f;
            unsigned bb = __float_as_uint(f);
            unsigned hb = bb >> 16;
            float hf = __uint_as_float(bb & 0xffff0000u);
            unsigned lb = __float_as_uint(f - hf) >> 16;
            halves[h] = p ? lb : hb;
        }
    }
    reinterpret_cast<unsigned*>(ws)[idx] = halves[0] | (halves[1] << 16);
}

__global__ __launch_bounds__(256) void cvx_quad_kernel(
    const float* __restrict__ z, const float* __restrict__ t,
    const float* __restrict__ ws, const float* __restrict__ b2,
    float* __restrict__ out, int B, int ntiles, int tpw)
{
    __shared__ float lds[4 * 2240];
    int lane = threadIdx.x & 63;
    int wid  = threadIdx.x >> 6;
    float* wbase = lds + wid * 2240;          // [16][132] Y tile (f32)
    float* pbase = wbase + 16 * 132;          // [16][8]  P tile (f32)
    int g = lane >> 4, c15 = lane & 15;

    int gw = blockIdx.x * 4 + wid;
    int t0 = gw * tpw;
    if (t0 >= ntiles) return;
    int tend = t0 + tpw; if (tend > ntiles) tend = ntiles;

    // resident weight fragments
    const uint4v* wsv = reinterpret_cast<const uint4v*>(ws);
    uint4v b1f[7][2], b2f[4][2];
    #pragma unroll
    for (int tt = 0; tt < 7; ++tt) {
        b1f[tt][0] = wsv[(tt * 2 + 0) * 64 + lane];
        b1f[tt][1] = wsv[(tt * 2 + 1) * 64 + lane];
    }
    #pragma unroll
    for (int s = 0; s < 4; ++s) {
        b2f[s][0] = wsv[896 + (s * 2 + 0) * 64 + lane];
        b2f[s][1] = wsv[896 + (s * 2 + 1) * 64 + lane];
    }
    float bb[6];
    #pragma unroll
    for (int c = 0; c < 6; ++c) bb[c] = b2[6 + c];

    // zero the k in [112,128) pad of the Y tile (read by GEMM2 slice 3)
    {
        int i = lane * 4, m = i >> 4, c = i & 15;
        float4 zz; zz.x = 0.f; zz.y = 0.f; zz.z = 0.f; zz.w = 0.f;
        *reinterpret_cast<float4*>(wbase + m * 132 + 112 + c) = zz;
    }

    auto LOADX = [&](int tile, float xv[8]) {
        int row = tile * 16 + c15; if (row >= B) row = B - 1;
        const float* zr = z + (size_t)row * 12;
        if (g == 0) {
            float4 za = *reinterpret_cast<const float4*>(zr);
            float2 zb = *reinterpret_cast<const float2*>(zr + 4);
            float  zc = zr[6];
            xv[0] = t[row]; xv[1] = za.x; xv[2] = za.y; xv[3] = za.z;
            xv[4] = za.w;   xv[5] = zb.x; xv[6] = zb.y; xv[7] = zc;
        } else if (g == 1) {
            float  zd = zr[7];
            float4 ze = *reinterpret_cast<const float4*>(zr + 8);
            xv[0] = zd;   xv[1] = ze.x; xv[2] = ze.y; xv[3] = ze.z;
            xv[4] = ze.w; xv[5] = 1.0f; xv[6] = 0.0f; xv[7] = 0.0f;
        } else {
            #pragma unroll
            for (int i2 = 0; i2 < 8; ++i2) xv[i2] = 0.0f;
        }
    };

    float xcur[8];
    LOADX(t0, xcur);

    for (int tt = t0; tt < tend; ++tt) {
        // build A1 fragments (hi/lo) from current X row segment
        uint4v ah, al;
        {
            HiLo r0 = split2(xcur[0], xcur[1]);
            HiLo r1 = split2(xcur[2], xcur[3]);
            HiLo r2 = split2(xcur[4], xcur[5]);
            HiLo r3 = split2(xcur[6], xcur[7]);
            ah.x = r0.h; al.x = r0.l;
            ah.y = r1.h; al.y = r1.l;
            ah.z = r2.h; al.z = r2.l;
            ah.w = r3.h; al.w = r3.l;
        }
        if (tt + 1 < tend) LOADX(tt + 1, xcur);   // prefetch next tile

        bf16x8 A1h = __builtin_bit_cast(bf16x8, ah);
        bf16x8 A1l = __builtin_bit_cast(bf16x8, al);

        // GEMM1 + tanh + Y-tile write, one 16-col N-tile at a time
        #pragma unroll
        for (int nt = 0; nt < 7; ++nt) {
            f32x4 acc = {0.f, 0.f, 0.f, 0.f};
            bf16x8 Bh = __builtin_bit_cast(bf16x8, b1f[nt][0]);
            bf16x8 Bl = __builtin_bit_cast(bf16x8, b1f[nt][1]);
            acc = __builtin_amdgcn_mfma_f32_16x16x32_bf16(A1h, Bh, acc, 0, 0, 0);
            acc = __builtin_amdgcn_mfma_f32_16x16x32_bf16(A1h, Bl, acc, 0, 0, 0);
            acc = __builtin_amdgcn_mfma_f32_16x16x32_bf16(A1l, Bh, acc, 0, 0, 0);
            #pragma unroll
            for (int r = 0; r < 4; ++r) {
                float e  = __builtin_amdgcn_exp2f(acc[r] * TWO_LOG2E);
                float th = fmaf(-2.0f, fast_rcp(e + 1.0f), 1.0f);
                wbase[(g * 4 + r) * 132 + nt * 16 + c15] = th;
            }
        }

        // GEMM2: A2 from Y tile (transposed read), K = 128 in 4 slices
        f32x4 p = {0.f, 0.f, 0.f, 0.f};
        #pragma unroll
        for (int s = 0; s < 4; ++s) {
            const float* src = wbase + c15 * 132 + s * 32 + g * 8;
            float4 v0 = *reinterpret_cast<const float4*>(src);
            float4 v1 = *reinterpret_cast<const float4*>(src + 4);
            uint4v a2h, a2l;
            {
                HiLo r0 = split2(v0.x, v0.y);
                HiLo r1 = split2(v0.z, v0.w);
                HiLo r2 = split2(v1.x, v1.y);
                HiLo r3 = split2(v1.z, v1.w);
                a2h.x = r0.h; a2l.x = r0.l;
                a2h.y = r1.h; a2l.y = r1.l;
                a2h.z = r2.h; a2l.z = r2.l;
                a2h.w = r3.h; a2l.w = r3.l;
            }
            bf16x8 A2h = __builtin_bit_cast(bf16x8, a2h);
            bf16x8 A2l = __builtin_bit_cast(bf16x8, a2l);
            bf16x8 Bh = __builtin_bit_cast(bf16x8, b2f[s][0]);
            bf16x8 Bl = __builtin_bit_cast(bf16x8, b2f[s][1]);
            p = __builtin_amdgcn_mfma_f32_16x16x32_bf16(A2h, Bh, p, 0, 0, 0);
            p = __builtin_amdgcn_mfma_f32_16x16x32_bf16(A2h, Bl, p, 0, 0, 0);
            p = __builtin_amdgcn_mfma_f32_16x16x32_bf16(A2l, Bh, p, 0, 0, 0);
        }

        // transpose P (lane holds rows g*4+r of col c15) into [16][8] tile
        if (c15 < 6) {
            #pragma unroll
            for (int r = 0; r < 4; ++r) pbase[(g * 4 + r) * 8 + c15] = p[r];
        }

        // per-row epilogue: Lambert W argmin (16 lanes, one row each)
        if (lane < 16) {
            int m = lane;
            float4 pa = *reinterpret_cast<const float4*>(pbase + m * 8);
            float2 pb = *reinterpret_cast<const float2*>(pbase + m * 8 + 4);
            float p0 = pa.x + bb[0], p1 = pa.y + bb[1], p2 = pa.z + bb[2];
            float p3 = pa.w + bb[3], p4 = pb.x + bb[4], p5 = pb.y + bb[5];

            float c0 = 2.0f * (p0 + p1 + p2);   // / MASS, MASS = 0.5
            float x = fmaf(c0, c0, fmaf(p3, p3, fmaf(p4, p4, p5 * p5)));

            float w = __logf(1.0f + x);
            #pragma unroll
            for (int it = 0; it < 5; ++it) {
                float ew  = __expf(w);
                float num = fmaf(w, ew, -x);
                float den = fmaf(ew, w, ew);
                w = w - num * fast_rcp(den);
            }
            float sc = -__expf(-0.5f * w);

            int row = tt * 16 + m;
            if (row < B) {
                float4 o;
                o.x = c0 * sc; o.y = p3 * sc; o.z = p4 * sc; o.w = p5 * sc;
                *reinterpret_cast<float4*>(out + (size_t)row * 4) = o;
            }
        }
    }
}

extern "C" void kernel_launch(void* const* d_in, const int* in_sizes, int n_in,
                              void* d_out, int out_size, void* d_ws, size_t ws_size,
                              hipStream_t stream) {
    const float* z  = (const float*)d_in[0];
    const float* t  = (const float*)d_in[1];
    const float* W1 = (const float*)d_in[2];
    const float* b1 = (const float*)d_in[3];
    const float* W2 = (const float*)d_in[4];
    const float* b2 = (const float*)d_in[5];
    float* out = (float*)d_out;
    float* ws  = (float*)d_ws;      // needs 5632 floats = 22.5 KB

    pack_weights<<<dim3(22), dim3(256), 0, stream>>>(W1, b1, W2, ws);

    int B = in_sizes[1];                       // t has B elements
    int ntiles = (B + 15) / 16;
    int tpw = (ntiles + 3124) / 3125;          // ~3125 waves => ~3 waves/SIMD
    int nwaves = (ntiles + tpw - 1) / tpw;
    int grid = (nwaves + 3) / 4;
    cvx_quad_kernel<<<dim3(grid), dim3(256), 0, stream>>>(
        z, t, ws, b2, out, B, ntiles, tpw);
}

// Round 6
// 104.124 us; speedup vs baseline: 1.1751x; 1.1751x over previous
//
#include <hip/hip_runtime.h>

// CVXPolicy_Quadcopter R12: MFMA v2.
//  - GEMM1: Y=X@W1' split-bf16 (hh+hl+lh), W1/b1 pre-scaled by 2*log2e.
//  - Streaming K-strip: per k-slice s, compute n-tiles 2s,2s+1 + tanh into a
//    [16][36] f32 strip, immediately consume as GEMM2 A-slice (single rounded
//    bf16 via add+v_perm), accumulate P with B2 split hi/lo (8 mfma).
//  - Wave-owned LDS only (no barriers): strip 576 f32 + P-stash [64][12].
//    21.5 KB/block -> ~7 blocks/CU; grid 1954 blocks (4 tiles/wave).
//  - Epilogue: batched over the wave's 4 tiles, all 64 lanes (1 row each).
// ws layout (dwords): region A: (t*2+p)*64+lane, t<7 (W1',b1' hi/lo planes)
//                     region B: 3584 + (s*2+p)*64+lane, s<4 (W2 hi/lo planes)

constexpr int S = 12;   // z features
constexpr int H = 100;  // hidden
#define TWO_LOG2E 2.8853900817779268f

typedef float f32x4 __attribute__((ext_vector_type(4)));
typedef __bf16 bf16x8 __attribute__((ext_vector_type(8)));
typedef unsigned int uint4v __attribute__((ext_vector_type(4)));

struct HiLo { unsigned h, l; };

__device__ __forceinline__ float fast_rcp(float x) {
    return __builtin_amdgcn_rcpf(x);
}

// split f32 pair into (hi-bf16 pair, lo-bf16 pair) packed words.
// elem (2d) -> low 16 bits, elem (2d+1) -> high 16 bits (matches pack_weights).
__device__ __forceinline__ HiLo split2(float f0, float f1) {
    unsigned b0 = __float_as_uint(f0), b1 = __float_as_uint(f1);
    float h0 = __uint_as_float(b0 & 0xffff0000u);
    float h1 = __uint_as_float(b1 & 0xffff0000u);
    unsigned l0 = __float_as_uint(f0 - h0) >> 16;
    unsigned l1 = __float_as_uint(f1 - h1) >> 16;
    HiLo r;
    r.h = (b0 >> 16) | (b1 & 0xffff0000u);
    r.l = l0 | (l1 << 16);
    return r;
}

// round-to-nearest bf16 pair: (a -> low16, b -> high16)
__device__ __forceinline__ unsigned pack_rnd(float a, float b) {
    unsigned ra = __float_as_uint(a) + 0x8000u;
    unsigned rb = __float_as_uint(b) + 0x8000u;
    return __builtin_amdgcn_perm(rb, ra, 0x07060302u);
}

__global__ __launch_bounds__(256) void pack_weights(
    const float* __restrict__ W1, const float* __restrict__ b1,
    const float* __restrict__ W2, float* __restrict__ ws)
{
    int idx = blockIdx.x * 256 + threadIdx.x;
    if (idx >= 5632) return;
    unsigned halves[2];
    if (idx < 3584) {
        int d = idx & 3, lane = (idx >> 2) & 63, tp = idx >> 8;
        int t = tp >> 1, p = tp & 1;
        int g = lane >> 4, n = (t << 4) + (lane & 15);
        #pragma unroll
        for (int h = 0; h < 2; ++h) {
            int k = g * 8 + 2 * d + h;
            float f = 0.0f;
            if (n < H) {
                if (k < 13)       f = W1[k * H + n] * TWO_LOG2E;
                else if (k == 13) f = b1[n] * TWO_LOG2E;
            }
            unsigned bb = __float_as_uint(f);
            unsigned hb = bb >> 16;
            float hf = __uint_as_float(bb & 0xffff0000u);
            unsigned lb = __float_as_uint(f - hf) >> 16;
            halves[h] = p ? lb : hb;
        }
    } else {
        int r = idx - 3584;
        int d = r & 3, lane = (r >> 2) & 63, sp = r >> 8;
        int s = sp >> 1, p = sp & 1;
        int g = lane >> 4, c = lane & 15;
        #pragma unroll
        for (int h = 0; h < 2; ++h) {
            int k = s * 32 + g * 8 + 2 * d + h;
            float f = (k < H && c < 6) ? W2[k * S + 6 + c] : 0.0f;
            unsigned bb = __float_as_uint(f);
            unsigned hb = bb >> 16;
            float hf = __uint_as_float(bb & 0xffff0000u);
            unsigned lb = __float_as_uint(f - hf) >> 16;
            halves[h] = p ? lb : hb;
        }
    }
    reinterpret_cast<unsigned*>(ws)[idx] = halves[0] | (halves[1] << 16);
}

__global__ __launch_bounds__(256) void cvx_quad_kernel(
    const float* __restrict__ z, const float* __restrict__ t,
    const float* __restrict__ ws, const float* __restrict__ b2,
    float* __restrict__ out, int B, int ntiles)
{
    __shared__ float lds[4 * 1344];
    int lane = threadIdx.x & 63;
    int wid  = threadIdx.x >> 6;
    float* strip = lds + wid * 1344;          // [16][36] f32 Y-strip
    float* pb    = strip + 576;               // [64][12] f32 P-stash
    int g = lane >> 4, c15 = lane & 15;

    int gw = blockIdx.x * 4 + wid;
    int t0 = gw * 4;
    if (t0 >= ntiles) return;
    int ntl = ntiles - t0; if (ntl > 4) ntl = 4;

    // resident weight fragments
    const uint4v* wsv = reinterpret_cast<const uint4v*>(ws);
    uint4v b1f[7][2], b2f[4][2];
    #pragma unroll
    for (int tt = 0; tt < 7; ++tt) {
        b1f[tt][0] = wsv[(tt * 2 + 0) * 64 + lane];
        b1f[tt][1] = wsv[(tt * 2 + 1) * 64 + lane];
    }
    #pragma unroll
    for (int s = 0; s < 4; ++s) {
        b2f[s][0] = wsv[896 + (s * 2 + 0) * 64 + lane];
        b2f[s][1] = wsv[896 + (s * 2 + 1) * 64 + lane];
    }
    float bb[6];
    #pragma unroll
    for (int c = 0; c < 6; ++c) bb[c] = b2[6 + c];

    auto LOADX = [&](int tile, float xv[8]) {
        int row = tile * 16 + c15; if (row >= B) row = B - 1;
        const float* zr = z + (size_t)row * 12;
        if (g == 0) {
            float4 za = *reinterpret_cast<const float4*>(zr);
            float2 zb = *reinterpret_cast<const float2*>(zr + 4);
            float  zc = zr[6];
            xv[0] = t[row]; xv[1] = za.x; xv[2] = za.y; xv[3] = za.z;
            xv[4] = za.w;   xv[5] = zb.x; xv[6] = zb.y; xv[7] = zc;
        } else if (g == 1) {
            float  zd = zr[7];
            float4 ze = *reinterpret_cast<const float4*>(zr + 8);
            xv[0] = zd;   xv[1] = ze.x; xv[2] = ze.y; xv[3] = ze.z;
            xv[4] = ze.w; xv[5] = 1.0f; xv[6] = 0.0f; xv[7] = 0.0f;
        } else {
            #pragma unroll
            for (int i2 = 0; i2 < 8; ++i2) xv[i2] = 0.0f;
        }
    };

    float xcur[8];
    LOADX(t0, xcur);

    for (int q = 0; q < ntl; ++q) {
        // A1 fragments (hi/lo split) from current X rows
        uint4v ah, al;
        {
            HiLo r0 = split2(xcur[0], xcur[1]);
            HiLo r1 = split2(xcur[2], xcur[3]);
            HiLo r2 = split2(xcur[4], xcur[5]);
            HiLo r3 = split2(xcur[6], xcur[7]);
            ah.x = r0.h; al.x = r0.l;
            ah.y = r1.h; al.y = r1.l;
            ah.z = r2.h; al.z = r2.l;
            ah.w = r3.h; al.w = r3.l;
        }
        if (q + 1 < ntl) LOADX(t0 + q + 1, xcur);   // prefetch
        bf16x8 A1h = __builtin_bit_cast(bf16x8, ah);
        bf16x8 A1l = __builtin_bit_cast(bf16x8, al);

        f32x4 p = {0.f, 0.f, 0.f, 0.f};
        #pragma unroll
        for (int s = 0; s < 4; ++s) {
            // GEMM1 n-tiles 2s (and 2s+1 when s<3)
            f32x4 acc0 = {0.f, 0.f, 0.f, 0.f};
            {
                bf16x8 Bh = __builtin_bit_cast(bf16x8, b1f[2 * s][0]);
                bf16x8 Bl = __builtin_bit_cast(bf16x8, b1f[2 * s][1]);
                acc0 = __builtin_amdgcn_mfma_f32_16x16x32_bf16(A1h, Bh, acc0, 0, 0, 0);
                acc0 = __builtin_amdgcn_mfma_f32_16x16x32_bf16(A1h, Bl, acc0, 0, 0, 0);
                acc0 = __builtin_amdgcn_mfma_f32_16x16x32_bf16(A1l, Bh, acc0, 0, 0, 0);
            }
            f32x4 acc1 = {0.f, 0.f, 0.f, 0.f};
            if (s < 3) {
                bf16x8 Bh = __builtin_bit_cast(bf16x8, b1f[2 * s + 1][0]);
                bf16x8 Bl = __builtin_bit_cast(bf16x8, b1f[2 * s + 1][1]);
                acc1 = __builtin_amdgcn_mfma_f32_16x16x32_bf16(A1h, Bh, acc1, 0, 0, 0);
                acc1 = __builtin_amdgcn_mfma_f32_16x16x32_bf16(A1h, Bl, acc1, 0, 0, 0);
                acc1 = __builtin_amdgcn_mfma_f32_16x16x32_bf16(A1l, Bh, acc1, 0, 0, 0);
            }

            // tanh (acc pre-scaled by 2*log2e): th = 1 - 2/(1+2^acc)
            #pragma unroll
            for (int r = 0; r < 4; ++r) {
                float e  = __builtin_amdgcn_exp2f(acc0[r]);
                float th = fmaf(-2.0f, fast_rcp(e + 1.0f), 1.0f);
                strip[(g * 4 + r) * 36 + c15] = th;
            }
            if (s < 3) {
                #pragma unroll
                for (int r = 0; r < 4; ++r) {
                    float e  = __builtin_amdgcn_exp2f(acc1[r]);
                    float th = fmaf(-2.0f, fast_rcp(e + 1.0f), 1.0f);
                    strip[(g * 4 + r) * 36 + 16 + c15] = th;
                }
            }

            // GEMM2 slice s: A2 = strip rows (transposed read), rounded bf16
            uint4v a2;
            if (s == 3 && g >= 2) {
                a2.x = 0u; a2.y = 0u; a2.z = 0u; a2.w = 0u;  // k>=112 pad
            } else {
                const float* src = strip + c15 * 36 + g * 8;
                float4 v0 = *reinterpret_cast<const float4*>(src);
                float4 v1 = *reinterpret_cast<const float4*>(src + 4);
                a2.x = pack_rnd(v0.x, v0.y);
                a2.y = pack_rnd(v0.z, v0.w);
                a2.z = pack_rnd(v1.x, v1.y);
                a2.w = pack_rnd(v1.z, v1.w);
            }
            bf16x8 A2 = __builtin_bit_cast(bf16x8, a2);
            bf16x8 B2h = __builtin_bit_cast(bf16x8, b2f[s][0]);
            bf16x8 B2l = __builtin_bit_cast(bf16x8, b2f[s][1]);
            p = __builtin_amdgcn_mfma_f32_16x16x32_bf16(A2, B2h, p, 0, 0, 0);
            p = __builtin_amdgcn_mfma_f32_16x16x32_bf16(A2, B2l, p, 0, 0, 0);
        }

        // stash P rows for batched epilogue (lane holds col c15, rows g*4+r)
        if (c15 < 6) {
            #pragma unroll
            for (int r = 0; r < 4; ++r)
                pb[(q * 16 + g * 4 + r) * 12 + c15] = p[r];
        }
    }

    // wave-wide epilogue: 1 row per lane over the wave's <=64 rows
    if (lane < ntl * 16) {
        int row = t0 * 16 + lane;
        if (row < B) {
            const float* pr = pb + lane * 12;
            float4 pa = *reinterpret_cast<const float4*>(pr);
            float2 pv = *reinterpret_cast<const float2*>(pr + 4);
            float p0 = pa.x + bb[0], p1 = pa.y + bb[1], p2 = pa.z + bb[2];
            float p3 = pa.w + bb[3], p4 = pv.x + bb[4], p5 = pv.y + bb[5];

            float c0 = 2.0f * (p0 + p1 + p2);   // / MASS, MASS = 0.5
            float x = fmaf(c0, c0, fmaf(p3, p3, fmaf(p4, p4, p5 * p5)));

            float w = __logf(1.0f + x);
            #pragma unroll
            for (int it = 0; it < 5; ++it) {
                float ew  = __expf(w);
                float num = fmaf(w, ew, -x);
                float den = fmaf(ew, w, ew);
                w = w - num * fast_rcp(den);
            }
            float sc = -__expf(-0.5f * w);

            float4 o;
            o.x = c0 * sc; o.y = p3 * sc; o.z = p4 * sc; o.w = p5 * sc;
            *reinterpret_cast<float4*>(out + (size_t)row * 4) = o;
        }
    }
}

extern "C" void kernel_launch(void* const* d_in, const int* in_sizes, int n_in,
                              void* d_out, int out_size, void* d_ws, size_t ws_size,
                              hipStream_t stream) {
    const float* z  = (const float*)d_in[0];
    const float* t  = (const float*)d_in[1];
    const float* W1 = (const float*)d_in[2];
    const float* b1 = (const float*)d_in[3];
    const float* W2 = (const float*)d_in[4];
    const float* b2 = (const float*)d_in[5];
    float* out = (float*)d_out;
    float* ws  = (float*)d_ws;      // needs 5632 floats = 22.5 KB

    pack_weights<<<dim3(22), dim3(256), 0, stream>>>(W1, b1, W2, ws);

    int B = in_sizes[1];                       // t has B elements
    int ntiles = (B + 15) / 16;                // 16-row m-tiles
    int nwaves = (ntiles + 3) / 4;             // 4 tiles per wave
    int grid = (nwaves + 3) / 4;               // 4 waves per block
    cvx_quad_kernel<<<dim3(grid), dim3(256), 0, stream>>>(
        z, t, ws, b2, out, B, ntiles);
}